// Round 1
// baseline (1994.294 us; speedup 1.0000x reference)
//
#include <hip/hip_runtime.h>
#include <cstdint>
#include <cstddef>

typedef uint16_t u16;
typedef __attribute__((ext_vector_type(8))) short bf16x8;   // 8 bf16 = 4 VGPRs (guide §3)
typedef __attribute__((ext_vector_type(4))) float f32x4;
typedef __attribute__((ext_vector_type(4))) uint16_t u16x4;

#define GLOBAL_AS(p) (const __attribute__((address_space(1))) void*)(p)
#define LDS_AS(p)    (__attribute__((address_space(3))) void*)(p)

__device__ __forceinline__ u16 f2b(float f){
  uint32_t u = __float_as_uint(f);
  u += 0x7fff + ((u >> 16) & 1);            // RNE
  return (u16)(u >> 16);
}
__device__ __forceinline__ float b2f(u16 h){
  return __uint_as_float(((uint32_t)h) << 16);
}

// ---------------- fp32 -> bf16 convert (vector x4) ----------------
__global__ void cvt_bf16_kernel(const float* __restrict__ src, u16* __restrict__ dst, int n){
  int i = (blockIdx.x * 256 + threadIdx.x) * 4;
  if (i >= n) return;
  float4 f = *(const float4*)(src + i);
  u16x4 o; o.x = f2b(f.x); o.y = f2b(f.y); o.z = f2b(f.z); o.w = f2b(f.w);
  *(u16x4*)(dst + i) = o;
}

// ---------------- 512x512 bf16 transpose (batched, 64x64 tiles) ----------------
__global__ void transpose512_kernel(const u16* __restrict__ src, u16* __restrict__ dst){
  __shared__ u16 tile[64][68];               // pitch 68: 2-way LDS aliasing only (free, G4)
  size_t b = blockIdx.y;
  int t = blockIdx.x;
  int r0 = (t >> 3) * 64, c0 = (t & 7) * 64;
  const u16* s = src + b * 262144;
  u16* d = dst + b * 262144;
  int tx = threadIdx.x & 63, ty = threadIdx.x >> 6;
  #pragma unroll
  for (int k = 0; k < 16; k++){
    int r = ty * 16 + k;
    tile[r][tx] = s[(size_t)(r0 + r) * 512 + c0 + tx];
  }
  __syncthreads();
  #pragma unroll
  for (int k = 0; k < 16; k++){
    int c = ty * 16 + k;
    d[(size_t)(c0 + c) * 512 + r0 + tx] = tile[tx][c];
  }
}

// ---------------- row softmax: fp32 scores -> bf16 P; one wave per 512-row ----------------
__global__ void softmax_kernel(const float* __restrict__ S, u16* __restrict__ P){
  int row = blockIdx.x * 4 + (threadIdx.x >> 6);
  int lane = threadIdx.x & 63;
  const float* s = S + (size_t)row * 512;
  float v[8];
  float mx = -3.0e38f;
  #pragma unroll
  for (int i = 0; i < 8; i++){ v[i] = s[lane + i * 64]; mx = fmaxf(mx, v[i]); }
  #pragma unroll
  for (int o = 32; o > 0; o >>= 1) mx = fmaxf(mx, __shfl_xor(mx, o));
  float sum = 0.f;
  #pragma unroll
  for (int i = 0; i < 8; i++){ v[i] = __expf(v[i] - mx); sum += v[i]; }
  #pragma unroll
  for (int o = 32; o > 0; o >>= 1) sum += __shfl_xor(sum, o);
  float inv = 1.0f / sum;
  u16* p = P + (size_t)row * 512;
  #pragma unroll
  for (int i = 0; i < 8; i++) p[lane + i * 64] = f2b(v[i] * inv);
}

// ---------------- mean over L: out2 bf16 [b][512][512] -> fp32 [b][512] ----------------
__global__ void pool_kernel(const u16* __restrict__ O, float* __restrict__ out, int b0){
  size_t b = blockIdx.x;
  int t = threadIdx.x;
  const u16* p = O + b * 262144;
  float s0 = 0.f, s1 = 0.f;
  for (int l = 0; l < 512; l++){
    s0 += b2f(p[l * 512 + t]);
    s1 += b2f(p[l * 512 + t + 256]);
  }
  float* o = out + ((size_t)b0 + b) * 512;
  o[t]       = s0 * (1.0f / 512.0f);
  o[t + 256] = s1 * (1.0f / 512.0f);
}

// ---------------- bf16 MFMA GEMM: C[512,512] = A[512,K] @ B[512,K]^T (batched) ----------------
// m97-style: 128x128 tile, BK=32, 4 waves each 64x64 (4x4 of 16x16x32), global_load_lds width 16.
// SPLIT: A cols [0,512) from A0, [512,1024) from A1 (the [mix,q] concat), both lda=512.
template<bool SPLIT, bool TANH, typename CT>
__global__ __launch_bounds__(256, 2) void gemm_bt_kernel(
    const u16* __restrict__ A0, const u16* __restrict__ A1,
    const u16* __restrict__ B, CT* __restrict__ C,
    int K, int ldb, int64_t aBatch, int64_t bBatch, int64_t cBatch)
{
  __shared__ __align__(16) u16 As[128 * 32];
  __shared__ __align__(16) u16 Bs[128 * 32];
  int64_t bat = blockIdx.y;
  int m0 = (blockIdx.x >> 2) * 128, n0 = (blockIdx.x & 3) * 128;
  A0 += bat * aBatch;
  if (SPLIT) A1 += bat * aBatch;
  B += bat * bBatch;
  C += bat * cBatch;
  int tid = threadIdx.x, lane = tid & 63;
  int w = tid >> 6;
  int wm = (w >> 1) * 64, wn = (w & 1) * 64;
  f32x4 acc[4][4];
  #pragma unroll
  for (int i = 0; i < 4; i++)
    #pragma unroll
    for (int j = 0; j < 4; j++) acc[i][j] = (f32x4){0.f, 0.f, 0.f, 0.f};

  int sRow = tid >> 2, sCol = (tid & 3) * 8;   // staging: 16B per lane, row-major LDS = base + lane*16
  int fr = lane & 15, fq = (lane >> 4) * 8;    // frag: m/n = lane&15, k = quad*8+j (guide §3, verified)

  for (int k0 = 0; k0 < K; k0 += 32){
    const u16* Ap = A0; int kk = k0;
    if (SPLIT && k0 >= 512){ Ap = A1; kk = k0 - 512; }
    const u16* ga = Ap + (size_t)(m0 + sRow) * 512 + kk + sCol;
    const u16* gb = B  + (size_t)(n0 + sRow) * ldb + k0 + sCol;
    __builtin_amdgcn_global_load_lds(GLOBAL_AS(ga),                    LDS_AS(&As[tid * 8]),        16, 0, 0);
    __builtin_amdgcn_global_load_lds(GLOBAL_AS(ga + (size_t)64 * 512), LDS_AS(&As[2048 + tid * 8]), 16, 0, 0);
    __builtin_amdgcn_global_load_lds(GLOBAL_AS(gb),                    LDS_AS(&Bs[tid * 8]),        16, 0, 0);
    __builtin_amdgcn_global_load_lds(GLOBAL_AS(gb + (size_t)64 * ldb), LDS_AS(&Bs[2048 + tid * 8]), 16, 0, 0);
    __syncthreads();
    bf16x8 af[4], bfr[4];
    #pragma unroll
    for (int i = 0; i < 4; i++) af[i]  = *(const bf16x8*)&As[(wm + i * 16 + fr) * 32 + fq];
    #pragma unroll
    for (int j = 0; j < 4; j++) bfr[j] = *(const bf16x8*)&Bs[(wn + j * 16 + fr) * 32 + fq];
    #pragma unroll
    for (int i = 0; i < 4; i++)
      #pragma unroll
      for (int j = 0; j < 4; j++)
        acc[i][j] = __builtin_amdgcn_mfma_f32_16x16x32_bf16(af[i], bfr[j], acc[i][j], 0, 0, 0);
    __syncthreads();
  }
  // C/D layout: col = lane&15, row = (lane>>4)*4 + reg (guide §3, m89/m91-verified)
  int cq = (lane >> 4) * 4, cc = lane & 15;
  #pragma unroll
  for (int i = 0; i < 4; i++){
    #pragma unroll
    for (int j = 0; j < 4; j++){
      #pragma unroll
      for (int r = 0; r < 4; r++){
        int row = m0 + wm + i * 16 + cq + r;
        int col = n0 + wn + j * 16 + cc;
        float v = acc[i][j][r];
        if (TANH) v = tanhf(v);
        if constexpr (sizeof(CT) == 4) C[(size_t)row * 512 + col] = v;
        else                           C[(size_t)row * 512 + col] = f2b(v);
      }
    }
  }
}

extern "C" void kernel_launch(void* const* d_in, const int* in_sizes, int n_in,
                              void* d_out, int out_size, void* d_ws, size_t ws_size,
                              hipStream_t stream) {
  const float* emb   = (const float*)d_in[0];   // [256,512,512]
  const float* Win1  = (const float*)d_in[1];   // [512,512]
  const float* Wout1 = (const float*)d_in[2];   // [512,1024]
  const float* Win2  = (const float*)d_in[3];
  const float* Wout2 = (const float*)d_in[4];
  float* out = (float*)d_out;                   // [256,512]

  // chunk over batches so workspace fits: need 4MB (weights) + CB*4MB
  int CB = 64;
  while (CB > 1 && (4ull << 20) + (size_t)CB * (262144ull * 16) > ws_size) CB >>= 1;
  const int64_t S = (int64_t)CB * 262144;       // elems per chunk buffer

  char* wsb = (char*)d_ws;
  u16* Win1b  = (u16*)wsb;                      // 512*512
  u16* Wout1b = Win1b + 262144;                 // 512*1024
  u16* Win2b  = Wout1b + 524288;
  u16* Wout2b = Win2b + 262144;
  u16* base = (u16*)(wsb + (4 << 20));
  u16* xb   = base;            // x (block1) bf16
  u16* x2b  = xb + S;          // x2 bf16
  u16* qb   = x2b + S;         // q bf16
  u16* mixb = qb + S;          // mix bf16
  u16* xTb  = mixb + S;        // x^T bf16
  float* scb = (float*)(xTb + S);   // scores fp32 (S floats)
  u16* Pb   = (u16*)(scb + S);      // P bf16
  u16* out2b = (u16*)scb;           // out2 bf16 aliases scores region (scores dead by then)

  // weights -> bf16 (re-done every call: ws is re-poisoned by harness)
  cvt_bf16_kernel<<<256, 256, 0, stream>>>(Win1,  Win1b,  262144);
  cvt_bf16_kernel<<<512, 256, 0, stream>>>(Wout1, Wout1b, 524288);
  cvt_bf16_kernel<<<256, 256, 0, stream>>>(Win2,  Win2b,  262144);
  cvt_bf16_kernel<<<512, 256, 0, stream>>>(Wout2, Wout2b, 524288);

  dim3 gg(16, CB);        // 4x4 output tiles of 128, CB batches
  dim3 gt(64, CB);        // transpose tiles
  const int64_t s1 = 262144;  // per-batch elem stride

  for (int c = 0; c < 256 / CB; c++){
    const float* embc = emb + (size_t)c * CB * 262144;
    cvt_bf16_kernel<<<CB * 256, 256, 0, stream>>>(embc, xb, CB * 262144);

    // ---- block 1 (tanh) ----
    gemm_bt_kernel<false,false,u16><<<gg, 256, 0, stream>>>(xb, nullptr, Win1b, qb, 512, 512, s1, 0, s1);
    transpose512_kernel<<<gt, 256, 0, stream>>>(xb, xTb);
    gemm_bt_kernel<false,false,float><<<gg, 256, 0, stream>>>(qb, nullptr, xb, scb, 512, 512, s1, s1, s1);
    softmax_kernel<<<CB * 128, 256, 0, stream>>>(scb, Pb);
    gemm_bt_kernel<false,false,u16><<<gg, 256, 0, stream>>>(Pb, nullptr, xTb, mixb, 512, 512, s1, s1, s1);
    gemm_bt_kernel<true,true,u16><<<gg, 256, 0, stream>>>(mixb, qb, Wout1b, x2b, 1024, 1024, s1, 0, s1);

    // ---- block 2 (no tanh) ----
    gemm_bt_kernel<false,false,u16><<<gg, 256, 0, stream>>>(x2b, nullptr, Win2b, qb, 512, 512, s1, 0, s1);
    transpose512_kernel<<<gt, 256, 0, stream>>>(x2b, xTb);
    gemm_bt_kernel<false,false,float><<<gg, 256, 0, stream>>>(qb, nullptr, x2b, scb, 512, 512, s1, s1, s1);
    softmax_kernel<<<CB * 128, 256, 0, stream>>>(scb, Pb);
    gemm_bt_kernel<false,false,u16><<<gg, 256, 0, stream>>>(Pb, nullptr, xTb, mixb, 512, 512, s1, s1, s1);
    gemm_bt_kernel<true,false,u16><<<gg, 256, 0, stream>>>(mixb, qb, Wout2b, out2b, 1024, 1024, s1, 0, s1);

    pool_kernel<<<CB, 256, 0, stream>>>(out2b, out, c * CB);
  }
}

// Round 2
// 1886.531 us; speedup vs baseline: 1.0571x; 1.0571x over previous
//
#include <hip/hip_runtime.h>
#include <cstdint>
#include <cstddef>

typedef uint16_t u16;
typedef __attribute__((ext_vector_type(8))) short bf16x8;   // 8 bf16 = 4 VGPRs (guide §3)
typedef __attribute__((ext_vector_type(4))) float f32x4;
typedef __attribute__((ext_vector_type(4))) uint16_t u16x4;

#define GLOBAL_AS(p) (const __attribute__((address_space(1))) void*)(p)
#define LDS_AS(p)    (__attribute__((address_space(3))) void*)(p)

__device__ __forceinline__ u16 f2b(float f){
  uint32_t u = __float_as_uint(f);
  u += 0x7fff + ((u >> 16) & 1);            // RNE
  return (u16)(u >> 16);
}
__device__ __forceinline__ float b2f(u16 h){
  return __uint_as_float(((uint32_t)h) << 16);
}

// ---------------- fp32 -> bf16 convert (vector x4) ----------------
__global__ void cvt_bf16_kernel(const float* __restrict__ src, u16* __restrict__ dst, int n){
  int i = (blockIdx.x * 256 + threadIdx.x) * 4;
  if (i >= n) return;
  float4 f = *(const float4*)(src + i);
  u16x4 o; o.x = f2b(f.x); o.y = f2b(f.y); o.z = f2b(f.z); o.w = f2b(f.w);
  *(u16x4*)(dst + i) = o;
}

// ------- fused fp32->bf16 convert + copy + transpose (block-1 input path) -------
// reads emb fp32 once, writes x (bf16) and x^T (bf16). 64x64 tiles.
__global__ void cvtT_kernel(const float* __restrict__ src, u16* __restrict__ x, u16* __restrict__ xT){
  __shared__ u16 tile[64][68];               // pitch 68: only 2-way LDS aliasing (free, G4)
  size_t b = blockIdx.y;
  int t = blockIdx.x;
  int r0 = (t >> 3) * 64, c0 = (t & 7) * 64;
  const float* s = src + b * 262144;
  u16* dx = x + b * 262144;
  u16* dT = xT + b * 262144;
  int tx = threadIdx.x & 63, ty = threadIdx.x >> 6;
  #pragma unroll
  for (int k = 0; k < 16; k++){
    int r = ty * 16 + k;
    u16 v = f2b(s[(size_t)(r0 + r) * 512 + c0 + tx]);
    dx[(size_t)(r0 + r) * 512 + c0 + tx] = v;
    tile[r][tx] = v;
  }
  __syncthreads();
  #pragma unroll
  for (int k = 0; k < 16; k++){
    int c = ty * 16 + k;
    dT[(size_t)(c0 + c) * 512 + r0 + tx] = tile[tx][c];
  }
}

// ---------------- 512x512 bf16 transpose (batched, 64x64 tiles) ----------------
__global__ void transpose512_kernel(const u16* __restrict__ src, u16* __restrict__ dst){
  __shared__ u16 tile[64][68];
  size_t b = blockIdx.y;
  int t = blockIdx.x;
  int r0 = (t >> 3) * 64, c0 = (t & 7) * 64;
  const u16* s = src + b * 262144;
  u16* d = dst + b * 262144;
  int tx = threadIdx.x & 63, ty = threadIdx.x >> 6;
  #pragma unroll
  for (int k = 0; k < 16; k++){
    int r = ty * 16 + k;
    tile[r][tx] = s[(size_t)(r0 + r) * 512 + c0 + tx];
  }
  __syncthreads();
  #pragma unroll
  for (int k = 0; k < 16; k++){
    int c = ty * 16 + k;
    d[(size_t)(c0 + c) * 512 + r0 + tx] = tile[tx][c];
  }
}

// ---------------- row softmax: fp32 scores -> bf16 P; one wave per 512-row ----------------
__global__ void softmax_kernel(const float* __restrict__ S, u16* __restrict__ P){
  int row = blockIdx.x * 4 + (threadIdx.x >> 6);
  int lane = threadIdx.x & 63;
  const float* s = S + (size_t)row * 512;
  float v[8];
  float mx = -3.0e38f;
  #pragma unroll
  for (int i = 0; i < 8; i++){ v[i] = s[lane + i * 64]; mx = fmaxf(mx, v[i]); }
  #pragma unroll
  for (int o = 32; o > 0; o >>= 1) mx = fmaxf(mx, __shfl_xor(mx, o));
  float sum = 0.f;
  #pragma unroll
  for (int i = 0; i < 8; i++){ v[i] = __expf(v[i] - mx); sum += v[i]; }
  #pragma unroll
  for (int o = 32; o > 0; o >>= 1) sum += __shfl_xor(sum, o);
  float inv = 1.0f / sum;
  u16* p = P + (size_t)row * 512;
  #pragma unroll
  for (int i = 0; i < 8; i++) p[lane + i * 64] = f2b(v[i] * inv);
}

// ---------------- bf16 MFMA GEMM: C[512,512] = A[512,K] @ B[512,K]^T (batched) ----------------
// m97-style: 128x128 tile, BK=32, 4 waves each 64x64 (4x4 of 16x16x32), global_load_lds width 16.
// SPLIT: A cols [0,512) from A0, [512,1024) from A1 (the [mix,q] concat), both lda=512.
// POOL: no C store; column-sum/512 is atomically accumulated into poolOut[b][col] (mean over L).
template<bool SPLIT, bool TANH, bool POOL, typename CT>
__global__ __launch_bounds__(256, 2) void gemm_bt_kernel(
    const u16* __restrict__ A0, const u16* __restrict__ A1,
    const u16* __restrict__ B, CT* __restrict__ C,
    int K, int ldb, int64_t aBatch, int64_t bBatch, int64_t cBatch,
    float* __restrict__ poolOut, int b0)
{
  __shared__ __align__(16) u16 As[128 * 32];
  __shared__ __align__(16) u16 Bs[128 * 32];
  int64_t bat = blockIdx.y;
  int m0 = (blockIdx.x >> 2) * 128, n0 = (blockIdx.x & 3) * 128;
  A0 += bat * aBatch;
  if (SPLIT) A1 += bat * aBatch;
  B += bat * bBatch;
  if (!POOL) C += bat * cBatch;
  int tid = threadIdx.x, lane = tid & 63;
  int w = tid >> 6;
  int wm = (w >> 1) * 64, wn = (w & 1) * 64;
  f32x4 acc[4][4];
  #pragma unroll
  for (int i = 0; i < 4; i++)
    #pragma unroll
    for (int j = 0; j < 4; j++) acc[i][j] = (f32x4){0.f, 0.f, 0.f, 0.f};

  int sRow = tid >> 2, sCol = (tid & 3) * 8;   // staging: 16B per lane, row-major LDS = base + lane*16
  int fr = lane & 15, fq = (lane >> 4) * 8;    // frag: m/n = lane&15, k = quad*8+j (guide §3, verified)

  for (int k0 = 0; k0 < K; k0 += 32){
    const u16* Ap = A0; int kk = k0;
    if (SPLIT && k0 >= 512){ Ap = A1; kk = k0 - 512; }
    const u16* ga = Ap + (size_t)(m0 + sRow) * 512 + kk + sCol;
    const u16* gb = B  + (size_t)(n0 + sRow) * ldb + k0 + sCol;
    __builtin_amdgcn_global_load_lds(GLOBAL_AS(ga),                    LDS_AS(&As[tid * 8]),        16, 0, 0);
    __builtin_amdgcn_global_load_lds(GLOBAL_AS(ga + (size_t)64 * 512), LDS_AS(&As[2048 + tid * 8]), 16, 0, 0);
    __builtin_amdgcn_global_load_lds(GLOBAL_AS(gb),                    LDS_AS(&Bs[tid * 8]),        16, 0, 0);
    __builtin_amdgcn_global_load_lds(GLOBAL_AS(gb + (size_t)64 * ldb), LDS_AS(&Bs[2048 + tid * 8]), 16, 0, 0);
    __syncthreads();
    bf16x8 af[4], bfr[4];
    #pragma unroll
    for (int i = 0; i < 4; i++) af[i]  = *(const bf16x8*)&As[(wm + i * 16 + fr) * 32 + fq];
    #pragma unroll
    for (int j = 0; j < 4; j++) bfr[j] = *(const bf16x8*)&Bs[(wn + j * 16 + fr) * 32 + fq];
    #pragma unroll
    for (int i = 0; i < 4; i++)
      #pragma unroll
      for (int j = 0; j < 4; j++)
        acc[i][j] = __builtin_amdgcn_mfma_f32_16x16x32_bf16(af[i], bfr[j], acc[i][j], 0, 0, 0);
    __syncthreads();
  }

  if constexpr (POOL){
    // mean over rows (L): per wave sum its 64 rows per column, cross-quad shfl reduce,
    // then one atomicAdd per (col, j-frag) from lanes 0..15. 8 adds/address total.
    #pragma unroll
    for (int j = 0; j < 4; j++){
      float p = 0.f;
      #pragma unroll
      for (int i = 0; i < 4; i++)
        #pragma unroll
        for (int r = 0; r < 4; r++) p += acc[i][j][r];
      p += __shfl_xor(p, 16);
      p += __shfl_xor(p, 32);
      if (lane < 16){
        int col = n0 + wn + j * 16 + lane;
        atomicAdd(poolOut + ((size_t)(b0) + bat) * 512 + col, p * (1.0f / 512.0f));
      }
    }
  } else {
    // C/D layout: col = lane&15, row = (lane>>4)*4 + reg (guide §3, m89/m91-verified)
    int cq = (lane >> 4) * 4, cc = lane & 15;
    #pragma unroll
    for (int i = 0; i < 4; i++){
      #pragma unroll
      for (int j = 0; j < 4; j++){
        #pragma unroll
        for (int r = 0; r < 4; r++){
          int row = m0 + wm + i * 16 + cq + r;
          int col = n0 + wn + j * 16 + cc;
          float v = acc[i][j][r];
          if (TANH) v = tanhf(v);
          if constexpr (sizeof(CT) == 4) C[(size_t)row * 512 + col] = v;
          else                           C[(size_t)row * 512 + col] = f2b(v);
        }
      }
    }
  }
}

extern "C" void kernel_launch(void* const* d_in, const int* in_sizes, int n_in,
                              void* d_out, int out_size, void* d_ws, size_t ws_size,
                              hipStream_t stream) {
  const float* emb   = (const float*)d_in[0];   // [256,512,512]
  const float* Win1  = (const float*)d_in[1];   // [512,512]
  const float* Wout1 = (const float*)d_in[2];   // [512,1024]
  const float* Win2  = (const float*)d_in[3];
  const float* Wout2 = (const float*)d_in[4];
  float* out = (float*)d_out;                   // [256,512]

  // workspace: 4 MB weights + CB * 3 MB (aliased region plan, see per-step map below)
  int CB = 256;
  while (CB > 1 && (4ull << 20) + (size_t)CB * (3ull << 20) > ws_size) CB >>= 1;
  const int64_t E = 262144;                     // one 512x512 bf16 buffer, elems

  char* wsb = (char*)d_ws;
  u16* Win1b  = (u16*)wsb;                      // 512*512
  u16* Wout1b = Win1b + 262144;                 // 512*1024
  u16* Win2b  = Wout1b + 524288;
  u16* Wout2b = Win2b + 262144;
  u16* base = (u16*)(wsb + (4 << 20));
  // regions (per-batch live-range aliased):
  //   Ar: x1 -> mix1 -> P2        Br: q1 -> q2        Cr: xT1 -> x2 -> mix2
  //   Dr: scores(fp32) x2         Fr: P1 -> xT2
  u16*   Ar  = base;
  u16*   Br  = base + (size_t)CB * E;
  u16*   Cr  = base + 2 * (size_t)CB * E;
  float* Dr  = (float*)(base + 3 * (size_t)CB * E);   // CB * 262144 floats (2E u16 each)
  u16*   Fr  = base + 5 * (size_t)CB * E;

  hipMemsetAsync(d_out, 0, (size_t)out_size * sizeof(float), stream);

  // weights -> bf16 (re-done every call: ws is re-poisoned by harness)
  cvt_bf16_kernel<<<256, 256, 0, stream>>>(Win1,  Win1b,  262144);
  cvt_bf16_kernel<<<512, 256, 0, stream>>>(Wout1, Wout1b, 524288);
  cvt_bf16_kernel<<<256, 256, 0, stream>>>(Win2,  Win2b,  262144);
  cvt_bf16_kernel<<<512, 256, 0, stream>>>(Wout2, Wout2b, 524288);

  dim3 gg(16, CB);        // 4x4 output tiles of 128, CB batches
  dim3 gt(64, CB);        // transpose / cvtT tiles

  for (int c = 0; c < 256 / CB; c++){
    const float* embc = emb + (size_t)c * CB * 262144;
    int b0 = c * CB;

    // ---- block 1 (tanh) ----
    cvtT_kernel<<<gt, 256, 0, stream>>>(embc, Ar, Cr);                     // x1 -> Ar, xT1 -> Cr
    gemm_bt_kernel<false,false,false,u16><<<gg, 256, 0, stream>>>(
        Ar, nullptr, Win1b, Br, 512, 512, E, 0, E, nullptr, 0);            // q1 -> Br
    gemm_bt_kernel<false,false,false,float><<<gg, 256, 0, stream>>>(
        Br, nullptr, Ar, Dr, 512, 512, E, E, 262144, nullptr, 0);          // sc1 -> Dr
    softmax_kernel<<<CB * 128, 256, 0, stream>>>(Dr, Fr);                  // P1 -> Fr
    gemm_bt_kernel<false,false,false,u16><<<gg, 256, 0, stream>>>(
        Fr, nullptr, Cr, Ar, 512, 512, E, E, E, nullptr, 0);               // mix1 -> Ar
    gemm_bt_kernel<true,true,false,u16><<<gg, 256, 0, stream>>>(
        Ar, Br, Wout1b, Cr, 1024, 1024, E, 0, E, nullptr, 0);              // x2 -> Cr (tanh)

    // ---- block 2 (no tanh) + fused mean-pool ----
    gemm_bt_kernel<false,false,false,u16><<<gg, 256, 0, stream>>>(
        Cr, nullptr, Win2b, Br, 512, 512, E, 0, E, nullptr, 0);            // q2 -> Br
    transpose512_kernel<<<gt, 256, 0, stream>>>(Cr, Fr);                   // xT2 -> Fr
    gemm_bt_kernel<false,false,false,float><<<gg, 256, 0, stream>>>(
        Br, nullptr, Cr, Dr, 512, 512, E, E, 262144, nullptr, 0);          // sc2 -> Dr
    softmax_kernel<<<CB * 128, 256, 0, stream>>>(Dr, Ar);                  // P2 -> Ar
    gemm_bt_kernel<false,false,false,u16><<<gg, 256, 0, stream>>>(
        Ar, nullptr, Fr, Cr, 512, 512, E, E, E, nullptr, 0);               // mix2 -> Cr
    gemm_bt_kernel<true,false,true,u16><<<gg, 256, 0, stream>>>(
        Cr, Br, Wout2b, (u16*)nullptr, 1024, 1024, E, 0, 0, out, b0);      // pooled out
  }
}